// Round 3
// baseline (808.568 us; speedup 1.0000x reference)
//
#include <hip/hip_runtime.h>
#include <math.h>

#define T_ 250
#define BL 2000        // 8 * 250
#define KIN 480        // P*F = 20*24
#define NFLAT 120000   // 24*5000

__device__ __forceinline__ float sigmoidf_(float x){ return 1.0f/(1.0f+expf(-x)); }
__device__ __forceinline__ float siluf_(float x){ return x*sigmoidf_(x); }
__device__ __forceinline__ float softplusf_(float x){ return (x > 20.0f) ? x : log1pf(expf(x)); }
__device__ __forceinline__ float seluf_(float x){
  const float sc = 1.0507009873554804934193349852946f;
  const float al = 1.6732632423543772848170429916717f;
  return x > 0.0f ? sc*x : sc*al*expm1f(x);
}

// DPP-based add: x + dpp_move(x). Runs on the VALU pipe (no LDS round-trip).
// CTRL: 0xB1 quad_perm xor1, 0x4E quad_perm xor2, 0x124 row_ror:4,
//       0x128 row_ror:8, 0x142 row_bcast15 (row r lane15 -> row r+1)
template<int CTRL>
__device__ __forceinline__ float dpp_add(float x) {
  int t = __builtin_amdgcn_update_dpp(0, __builtin_bit_cast(int, x), CTRL, 0xF, 0xF, true);
  return x + __builtin_bit_cast(float, t);
}

// ---------------------------------------------------------------------------
// Generic fp32 tiled GEMM: C[M,N] = A[M,K] * W[N,K]^T  (both row-major, K contig)
// epi: 0 = store, 1 = store softplus(acc + bias[n]), 2 = store selu(acc),
//      3 = atomicAdd (for split-K; C must be pre-zeroed)
// ---------------------------------------------------------------------------
template<int BM, int BN, int BK, int TM, int TN>
__global__ __launch_bounds__(256, 2) void gemm_nt(
    const float* __restrict__ A, const float* __restrict__ W,
    float* __restrict__ C, const float* __restrict__ bias,
    int M, int N, int K, int lda, int ldb, int ldc, int epi)
{
  static_assert(BK == 32, "BK must be 32");
  __shared__ float As[BK][BM + 4];
  __shared__ float Bs[BK][BN + 4];
  constexpr int TNX = BN / TN;
  constexpr int TMX = BM / TM;
  static_assert(TNX * TMX == 256, "256 threads required");
  constexpr int AF4 = BM * BK / 1024;   // float4 loads per thread for A tile
  constexpr int BF4 = BN * BK / 1024;

  const int tid = threadIdx.x;
  const int tx = tid % TNX;
  const int ty = tid / TNX;
  const int m0 = blockIdx.y * BM;
  const int n0 = blockIdx.x * BN;
  const int kchunk = K / (int)gridDim.z;
  const int k_begin = blockIdx.z * kchunk;
  const int k_end = k_begin + kchunk;

  float acc[TM][TN];
#pragma unroll
  for (int i = 0; i < TM; ++i)
#pragma unroll
    for (int j = 0; j < TN; ++j) acc[i][j] = 0.0f;

  for (int k0 = k_begin; k0 < k_end; k0 += BK) {
#pragma unroll
    for (int i = 0; i < AF4; ++i) {
      int fi = tid + 256 * i;
      int r = fi >> 3;               // BK/4 == 8 float4 per row
      int kc = (fi & 7) * 4;
      int m = m0 + r;
      float4 v = make_float4(0.f, 0.f, 0.f, 0.f);
      if (m < M) v = *(const float4*)(A + (size_t)m * lda + k0 + kc);
      As[kc + 0][r] = v.x; As[kc + 1][r] = v.y; As[kc + 2][r] = v.z; As[kc + 3][r] = v.w;
    }
#pragma unroll
    for (int i = 0; i < BF4; ++i) {
      int fi = tid + 256 * i;
      int r = fi >> 3;
      int kc = (fi & 7) * 4;
      int n = n0 + r;
      float4 v = make_float4(0.f, 0.f, 0.f, 0.f);
      if (n < N) v = *(const float4*)(W + (size_t)n * ldb + k0 + kc);
      Bs[kc + 0][r] = v.x; Bs[kc + 1][r] = v.y; Bs[kc + 2][r] = v.z; Bs[kc + 3][r] = v.w;
    }
    __syncthreads();
#pragma unroll
    for (int kk = 0; kk < BK; ++kk) {
      float a[TM], bb[TN];
#pragma unroll
      for (int i = 0; i < TM; ++i) a[i] = As[kk][ty * TM + i];
#pragma unroll
      for (int j = 0; j < TN; ++j) bb[j] = Bs[kk][tx * TN + j];
#pragma unroll
      for (int i = 0; i < TM; ++i)
#pragma unroll
        for (int j = 0; j < TN; ++j) acc[i][j] = fmaf(a[i], bb[j], acc[i][j]);
    }
    __syncthreads();
  }

#pragma unroll
  for (int i = 0; i < TM; ++i) {
    int m = m0 + ty * TM + i;
    if (m >= M) continue;
#pragma unroll
    for (int j = 0; j < TN; ++j) {
      int n = n0 + tx * TN + j;
      if (n >= N) continue;
      float v = acc[i][j];
      if (epi == 1) v = softplusf_(v + bias[n]);
      else if (epi == 2) v = seluf_(v);
      if (epi == 3) atomicAdd(&C[(size_t)m * ldc + n], v);
      else C[(size_t)m * ldc + n] = v;
    }
  }
}

// ---------------------------------------------------------------------------
// Depthwise causal conv1d (width 4) + bias + silu -> xc.
// ALSO replaces the z-half of xz with silu(z) in place (scan consumes it raw).
// ---------------------------------------------------------------------------
__global__ __launch_bounds__(256) void conv_silu(
    float* __restrict__ xz, const float* __restrict__ cw,
    const float* __restrict__ cb, float* __restrict__ xc)
{
  int id = blockIdx.x * 256 + threadIdx.x;
  if (id >= BL * 1024) return;
  int bl = id >> 10;
  int d = id & 1023;
  int l = bl % T_;
  float4 w4 = *(const float4*)(cw + d * 4);
  float s = cb[d];
  if (l >= 3) s = fmaf(xz[(size_t)(bl - 3) * 2048 + d], w4.x, s);
  if (l >= 2) s = fmaf(xz[(size_t)(bl - 2) * 2048 + d], w4.y, s);
  if (l >= 1) s = fmaf(xz[(size_t)(bl - 1) * 2048 + d], w4.z, s);
  s = fmaf(xz[(size_t)bl * 2048 + d], w4.w, s);
  xc[id] = siluf_(s);
  float z = xz[(size_t)bl * 2048 + 1024 + d];
  xz[(size_t)bl * 2048 + 1024 + d] = siluf_(z);
}

// ---------------------------------------------------------------------------
// Selective scan v3. Wave = 2 channels x (32 lanes x 2 states). 4096 waves
// (16/CU, 4/SIMD) for latency hiding. Reduction: 4 in-row DPP adds +
// row_bcast15 cross-row add -> channel totals on lanes 16 (c=0) / 48 (c=1).
// Depth-2 unconditional prefetch (l+2 overreads stay inside d_ws regions).
// Reads silu(z) precomputed by conv_silu; writes gated y into xz x-half.
// ---------------------------------------------------------------------------
__global__ __launch_bounds__(256) void scan_kernel(
    const float* __restrict__ dtb, const float* __restrict__ xc,
    const float* __restrict__ xdbl, float* __restrict__ xz,
    const float* __restrict__ A_log, const float* __restrict__ Dp)
{
  int tid = threadIdx.x;
  int wv = tid >> 6, lane = tid & 63;
  int c = lane >> 5;          // channel within the pair
  int u = lane & 31;          // state-pair index (states 2u, 2u+1)
  int w = blockIdx.x * 4 + wv;    // 0..4095
  int b = w >> 9;                 // batch
  int d = ((w & 511) << 1) + c;   // channel
  const float LOG2E = 1.4426950408889634f;
  float2 al = *(const float2*)(A_log + (size_t)d * 64 + u * 2);
  float am0 = -expf(al.x) * LOG2E;
  float am1 = -expf(al.y) * LOG2E;
  float Dv = Dp[d];
  float h0 = 0.f, h1 = 0.f;
  const float* dtp = dtb + (size_t)b * 256000 + d;
  const float* xp  = xc  + (size_t)b * 256000 + d;
  const float* zp  = xz  + (size_t)b * 512000 + 1024 + d;   // silu(z)
  float*       yp  = xz  + (size_t)b * 512000 + d;
  const float* bp  = xdbl + (size_t)b * 40000 + 32 + u * 2;
  const float* cp  = bp + 64;

  float dt_f[2], xv_f[2], sz_f[2];
  float2 B_f[2], C_f[2];
#pragma unroll
  for (int i = 0; i < 2; ++i) {
    dt_f[i] = dtp[i * 1024];
    xv_f[i] = xp[i * 1024];
    sz_f[i] = zp[i * 2048];
    B_f[i] = *(const float2*)(bp + i * 160);
    C_f[i] = *(const float2*)(cp + i * 160);
  }
  const bool outlane = (u == 16);   // lanes 16 and 48

#pragma unroll 2
  for (int l = 0; l < T_; ++l) {
    int slot = l & 1;
    float dt = dt_f[slot], xv = xv_f[slot], sz = sz_f[slot];
    float2 Bv = B_f[slot], Cv = C_f[slot];
    // prefetch step l+2 (unconditional; overreads stay inside d_ws)
    dt_f[slot] = dtp[(size_t)(l + 2) * 1024];
    xv_f[slot] = xp[(size_t)(l + 2) * 1024];
    sz_f[slot] = zp[(size_t)(l + 2) * 2048];
    B_f[slot]  = *(const float2*)(bp + (size_t)(l + 2) * 160);
    C_f[slot]  = *(const float2*)(cp + (size_t)(l + 2) * 160);

    float dtx = dt * xv;
    h0 = fmaf(h0, exp2f(dt * am0), dtx * Bv.x);
    h1 = fmaf(h1, exp2f(dt * am1), dtx * Bv.y);
    float p = fmaf(h1, Cv.y, h0 * Cv.x);
    p = dpp_add<0xB1>(p);    // xor 1
    p = dpp_add<0x4E>(p);    // xor 2
    p = dpp_add<0x124>(p);   // row_ror:4
    p = dpp_add<0x128>(p);   // row_ror:8  -> row sums in all 16 lanes
    p = dpp_add<0x142>(p);   // row_bcast15 -> ch totals on lanes 16-31 / 48-63
    if (outlane) yp[(size_t)l * 2048] = fmaf(xv, Dv, p) * sz;
  }
}

// ---------------------------------------------------------------------------
// Permute selu(out_proj) [2000][480] -> y_flat [8][120000] (f-major)
// ---------------------------------------------------------------------------
__global__ __launch_bounds__(256) void transpose_k(
    const float* __restrict__ ym, float* __restrict__ yfl)
{
  int id = blockIdx.x * 256 + threadIdx.x;
  if (id >= 8 * NFLAT) return;
  int b = id / NFLAT;
  int r = id % NFLAT;
  int f = r / 5000;
  int qq = r % 5000;
  int tt = qq / 20;
  int p = qq % 20;
  yfl[id] = ym[(size_t)(b * T_ + tt) * KIN + p * 24 + f];
}

// ---------------------------------------------------------------------------
// fc1 v2: r1[b][c] += sum_k yfl[b][k] * W1[c][k].
// 1536 blocks = 64 c-groups x 24 k-slices of 5000 (8-aligned).
// 24 waves/CU, 64 B of W per lane-iter -> enough bytes in flight for HBM BW.
// ---------------------------------------------------------------------------
__global__ __launch_bounds__(256) void fc1_kernel(
    const float* __restrict__ yfl, const float* __restrict__ W,
    float* __restrict__ r1)
{
  int blk = blockIdx.x;
  int ks = blk % 24;           // k-slice: [ks*5000, ks*5000+5000)
  int cg = blk / 24;           // 0..63 -> c0 = cg*8
  int wv = threadIdx.x >> 6;
  int lane = threadIdx.x & 63;
  int ca = cg * 8 + wv * 2;
  const float* Wa = W + (size_t)ca * NFLAT;
  const float* Wb = Wa + NFLAT;
  float acc[2][8];
#pragma unroll
  for (int cc = 0; cc < 2; ++cc)
#pragma unroll
    for (int b = 0; b < 8; ++b) acc[cc][b] = 0.0f;

  int kbase = ks * 5000;
  int kend = kbase + 5000;
  // 9 full iters + partial 10th (lanes 0..48) covers exactly 5000 floats
  for (int k = kbase + lane * 8; k + 8 <= kend; k += 512) {
    float4 wa0 = *(const float4*)(Wa + k);
    float4 wa1 = *(const float4*)(Wa + k + 4);
    float4 wb0 = *(const float4*)(Wb + k);
    float4 wb1 = *(const float4*)(Wb + k + 4);
#pragma unroll
    for (int b = 0; b < 8; ++b) {
      const float* yb = yfl + (size_t)b * NFLAT + k;
      float4 y0 = *(const float4*)(yb);
      float4 y1 = *(const float4*)(yb + 4);
      float s0 = acc[0][b], s1 = acc[1][b];
      s0 = fmaf(wa0.x, y0.x, s0); s0 = fmaf(wa0.y, y0.y, s0);
      s0 = fmaf(wa0.z, y0.z, s0); s0 = fmaf(wa0.w, y0.w, s0);
      s0 = fmaf(wa1.x, y1.x, s0); s0 = fmaf(wa1.y, y1.y, s0);
      s0 = fmaf(wa1.z, y1.z, s0); s0 = fmaf(wa1.w, y1.w, s0);
      s1 = fmaf(wb0.x, y0.x, s1); s1 = fmaf(wb0.y, y0.y, s1);
      s1 = fmaf(wb0.z, y0.z, s1); s1 = fmaf(wb0.w, y0.w, s1);
      s1 = fmaf(wb1.x, y1.x, s1); s1 = fmaf(wb1.y, y1.y, s1);
      s1 = fmaf(wb1.z, y1.z, s1); s1 = fmaf(wb1.w, y1.w, s1);
      acc[0][b] = s0; acc[1][b] = s1;
    }
  }
#pragma unroll
  for (int cc = 0; cc < 2; ++cc)
#pragma unroll
    for (int b = 0; b < 8; ++b) {
      float s = acc[cc][b];
      s += __shfl_xor(s, 1);
      s += __shfl_xor(s, 2);
      s += __shfl_xor(s, 4);
      s += __shfl_xor(s, 8);
      s += __shfl_xor(s, 16);
      s += __shfl_xor(s, 32);
      if (lane == 0) atomicAdd(&r1[b * 512 + ca + cc], s);
    }
}

// ---------------------------------------------------------------------------
// fc2: one wave per output (b,j): dot-512 + biases
// ---------------------------------------------------------------------------
__global__ __launch_bounds__(256) void fc2_kernel(
    const float* __restrict__ r1, const float* __restrict__ b1,
    const float* __restrict__ W2, const float* __restrict__ b2,
    float* __restrict__ r2)
{
  int wid = blockIdx.x * 4 + (threadIdx.x >> 6);   // 0..2047
  int lane = threadIdx.x & 63;
  int b = wid >> 8;
  int j = wid & 255;
  int off = lane * 8;
  float4 ya = *(const float4*)(r1 + b * 512 + off);
  float4 yb = *(const float4*)(r1 + b * 512 + off + 4);
  float4 ba = *(const float4*)(b1 + off);
  float4 bbv = *(const float4*)(b1 + off + 4);
  float4 wa = *(const float4*)(W2 + (size_t)j * 512 + off);
  float4 wb = *(const float4*)(W2 + (size_t)j * 512 + off + 4);
  float p = (ya.x + ba.x) * wa.x + (ya.y + ba.y) * wa.y +
            (ya.z + ba.z) * wa.z + (ya.w + ba.w) * wa.w +
            (yb.x + bbv.x) * wb.x + (yb.y + bbv.y) * wb.y +
            (yb.z + bbv.z) * wb.z + (yb.w + bbv.w) * wb.w;
  p += __shfl_xor(p, 1);
  p += __shfl_xor(p, 2);
  p += __shfl_xor(p, 4);
  p += __shfl_xor(p, 8);
  p += __shfl_xor(p, 16);
  p += __shfl_xor(p, 32);
  if (lane == 0) r2[b * 256 + j] = p + b2[j];
}

// ---------------------------------------------------------------------------
// fc3 + fc4 fused, single block
// ---------------------------------------------------------------------------
__global__ __launch_bounds__(256) void fc34_kernel(
    const float* __restrict__ r2, const float* __restrict__ W3,
    const float* __restrict__ b3, const float* __restrict__ W4,
    const float* __restrict__ b4, float* __restrict__ out)
{
  __shared__ float a3[512];
  int tid = threadIdx.x;
  for (int o = tid; o < 512; o += 256) {
    int b = o >> 6, j = o & 63;
    float s = b3[j];
    const float* rr = r2 + b * 256;
    const float* wr = W3 + j * 256;
    for (int c = 0; c < 256; c += 4) {
      float4 rv = *(const float4*)(rr + c);
      float4 wv = *(const float4*)(wr + c);
      s = fmaf(rv.x, wv.x, fmaf(rv.y, wv.y, fmaf(rv.z, wv.z, fmaf(rv.w, wv.w, s))));
    }
    a3[o] = s;
  }
  __syncthreads();
  if (tid < 64) {
    int b = tid >> 3, j = tid & 7;
    float s = b4[j];
    const float* ar = a3 + b * 64;
    const float* wr = W4 + j * 64;
    for (int c = 0; c < 64; ++c) s = fmaf(ar[c], wr[c], s);
    out[b * 8 + j] = s;
  }
}

// ---------------------------------------------------------------------------
extern "C" void kernel_launch(void* const* d_in, const int* in_sizes, int n_in,
                              void* d_out, int out_size, void* d_ws, size_t ws_size,
                              hipStream_t stream) {
  const float* x      = (const float*)d_in[0];   // [8,5000,24] == [2000][480]
  const float* w_in   = (const float*)d_in[1];   // [2048,512]
  const float* conv_w = (const float*)d_in[2];   // [1024,4]
  const float* conv_b = (const float*)d_in[3];   // [1024]
  const float* w_xp   = (const float*)d_in[4];   // [160,1024]
  const float* w_dt   = (const float*)d_in[5];   // [1024,32]
  const float* b_dt   = (const float*)d_in[6];   // [1024]
  const float* A_log  = (const float*)d_in[7];   // [1024,64]
  const float* Dp     = (const float*)d_in[8];   // [1024]
  const float* w_out  = (const float*)d_in[9];   // [512,1024]
  const float* w1 = (const float*)d_in[10];      // [512,120000]
  const float* b1 = (const float*)d_in[11];
  const float* w2 = (const float*)d_in[12];      // [256,512]
  const float* b2 = (const float*)d_in[13];
  const float* w3 = (const float*)d_in[14];      // [64,256]
  const float* b3 = (const float*)d_in[15];
  const float* w4 = (const float*)d_in[16];      // [8,64]
  const float* b4 = (const float*)d_in[17];
  float* out = (float*)d_out;

  float* ws   = (float*)d_ws;
  float* xz   = ws;                 // [2000][2048]  (x half -> gated y; z half -> silu(z))
  float* xc   = xz + 4096000;       // [2000][1024]
  float* dtb  = xc + 2048000;       // [2000][1024]
  float* ym   = dtb + 2048000;      // [2000][480]
  float* yfl  = ym + 960000;        // [8][120000]
  float* xdbl = yfl + 960000;       // [2000][160]
  float* r1   = xdbl + 320000;      // [8][512]
  float* r2   = r1 + 4096;          // [8][256]

  // zero the atomic accumulators (xdbl + r1, contiguous)
  hipMemsetAsync(xdbl, 0, (320000 + 4096) * sizeof(float), stream);

  // 1. in_proj: xz[2000][2048] = x[2000][480] @ Win[2048][512(^480)]^T
  gemm_nt<64, 128, 32, 4, 8><<<dim3(2048 / 128, (BL + 63) / 64, 1), 256, 0, stream>>>(
      x, w_in, xz, nullptr, BL, 2048, KIN, KIN, 512, 2048, 0);

  // 2. depthwise conv + silu (also silu's the z-half in place)
  conv_silu<<<(BL * 1024) / 256, 256, 0, stream>>>(xz, conv_w, conv_b, xc);

  // 3. x_proj (split-K=2, atomic): xdbl[2000][160] = xc @ Wxp^T
  gemm_nt<32, 64, 32, 1, 8><<<dim3(3, (BL + 31) / 32, 2), 256, 0, stream>>>(
      xc, w_xp, xdbl, nullptr, BL, 160, 1024, 1024, 1024, 160, 3);

  // 4. dt_proj + softplus: dtb[2000][1024] = softplus(xdbl[:, :32] @ Wdt^T + b_dt)
  gemm_nt<32, 64, 32, 1, 8><<<dim3(1024 / 64, (BL + 31) / 32, 1), 256, 0, stream>>>(
      xdbl, w_dt, dtb, b_dt, BL, 1024, 32, 160, 32, 1024, 1);

  // 5. selective scan -> gated y into xz x-half
  scan_kernel<<<1024, 256, 0, stream>>>(dtb, xc, xdbl, xz, A_log, Dp);

  // 6. out_proj + selu: ym[2000][480] = selu(yg @ Wout[480 rows]^T)
  gemm_nt<64, 64, 32, 4, 4><<<dim3((KIN + 63) / 64, (BL + 63) / 64, 1), 256, 0, stream>>>(
      xz, w_out, ym, nullptr, BL, KIN, 1024, 2048, 1024, KIN, 2);

  // 7. permute to y_flat
  transpose_k<<<(8 * NFLAT) / 256, 256, 0, stream>>>(ym, yfl);

  // 8. fc1 (atomic accumulate into r1)
  fc1_kernel<<<1536, 256, 0, stream>>>(yfl, w1, r1);

  // 9. fc2
  fc2_kernel<<<512, 256, 0, stream>>>(r1, b1, w2, b2, r2);

  // 10. fc3 + fc4
  fc34_kernel<<<1, 256, 0, stream>>>(r2, w3, b3, w4, b4, out);
}

// Round 4
// 755.147 us; speedup vs baseline: 1.0707x; 1.0707x over previous
//
#include <hip/hip_runtime.h>
#include <math.h>

#define T_ 250
#define BL 2000        // 8 * 250
#define KIN 480        // P*F = 20*24
#define NFLAT 120000   // 24*5000

__device__ __forceinline__ float sigmoidf_(float x){ return 1.0f/(1.0f+expf(-x)); }
__device__ __forceinline__ float siluf_(float x){ return x*sigmoidf_(x); }
__device__ __forceinline__ float softplusf_(float x){ return (x > 20.0f) ? x : log1pf(expf(x)); }
__device__ __forceinline__ float seluf_(float x){
  const float sc = 1.0507009873554804934193349852946f;
  const float al = 1.6732632423543772848170429916717f;
  return x > 0.0f ? sc*x : sc*al*expm1f(x);
}

// DPP-based add: x + dpp_move(x). Runs on the VALU pipe (no LDS round-trip).
template<int CTRL>
__device__ __forceinline__ float dpp_add(float x) {
  int t = __builtin_amdgcn_update_dpp(0, __builtin_bit_cast(int, x), CTRL, 0xF, 0xF, true);
  return x + __builtin_bit_cast(float, t);
}

// ---------------------------------------------------------------------------
// Generic fp32 tiled GEMM: C[M,N] = A[M,K] * W[N,K]^T  (both row-major, K contig)
// epi: 0 = store, 1 = store softplus(acc + bias[n]), 2 = store selu(acc),
//      3 = atomicAdd (for split-K; C must be pre-zeroed)
// Inner loop uses ds_read_b128 fragment loads (row pitch BM+4 floats is 16B-mult).
// ---------------------------------------------------------------------------
template<int BM, int BN, int BK, int TM, int TN>
__global__ __launch_bounds__(256, 2) void gemm_nt(
    const float* __restrict__ A, const float* __restrict__ W,
    float* __restrict__ C, const float* __restrict__ bias,
    int M, int N, int K, int lda, int ldb, int ldc, int epi)
{
  static_assert(BK == 32, "BK must be 32");
  __shared__ __align__(16) float As[BK][BM + 4];
  __shared__ __align__(16) float Bs[BK][BN + 4];
  constexpr int TNX = BN / TN;
  constexpr int TMX = BM / TM;
  static_assert(TNX * TMX == 256, "256 threads required");
  constexpr int AF4 = BM * BK / 1024;   // float4 loads per thread for A tile
  constexpr int BF4 = BN * BK / 1024;

  const int tid = threadIdx.x;
  const int tx = tid % TNX;
  const int ty = tid / TNX;
  const int m0 = blockIdx.y * BM;
  const int n0 = blockIdx.x * BN;
  const int kchunk = K / (int)gridDim.z;
  const int k_begin = blockIdx.z * kchunk;
  const int k_end = k_begin + kchunk;

  float acc[TM][TN];
#pragma unroll
  for (int i = 0; i < TM; ++i)
#pragma unroll
    for (int j = 0; j < TN; ++j) acc[i][j] = 0.0f;

  for (int k0 = k_begin; k0 < k_end; k0 += BK) {
#pragma unroll
    for (int i = 0; i < AF4; ++i) {
      int fi = tid + 256 * i;
      int r = fi >> 3;               // BK/4 == 8 float4 per row
      int kc = (fi & 7) * 4;
      int m = m0 + r;
      float4 v = make_float4(0.f, 0.f, 0.f, 0.f);
      if (m < M) v = *(const float4*)(A + (size_t)m * lda + k0 + kc);
      As[kc + 0][r] = v.x; As[kc + 1][r] = v.y; As[kc + 2][r] = v.z; As[kc + 3][r] = v.w;
    }
#pragma unroll
    for (int i = 0; i < BF4; ++i) {
      int fi = tid + 256 * i;
      int r = fi >> 3;
      int kc = (fi & 7) * 4;
      int n = n0 + r;
      float4 v = make_float4(0.f, 0.f, 0.f, 0.f);
      if (n < N) v = *(const float4*)(W + (size_t)n * ldb + k0 + kc);
      Bs[kc + 0][r] = v.x; Bs[kc + 1][r] = v.y; Bs[kc + 2][r] = v.z; Bs[kc + 3][r] = v.w;
    }
    __syncthreads();
#pragma unroll
    for (int kk = 0; kk < BK; ++kk) {
      float a[TM], bb[TN];
      if constexpr ((TM & 3) == 0) {
#pragma unroll
        for (int t = 0; t < TM / 4; ++t) {
          float4 v = *(const float4*)&As[kk][ty * TM + t * 4];
          a[t*4+0] = v.x; a[t*4+1] = v.y; a[t*4+2] = v.z; a[t*4+3] = v.w;
        }
      } else {
#pragma unroll
        for (int i = 0; i < TM; ++i) a[i] = As[kk][ty * TM + i];
      }
      if constexpr ((TN & 3) == 0) {
#pragma unroll
        for (int t = 0; t < TN / 4; ++t) {
          float4 v = *(const float4*)&Bs[kk][tx * TN + t * 4];
          bb[t*4+0] = v.x; bb[t*4+1] = v.y; bb[t*4+2] = v.z; bb[t*4+3] = v.w;
        }
      } else {
#pragma unroll
        for (int j = 0; j < TN; ++j) bb[j] = Bs[kk][tx * TN + j];
      }
#pragma unroll
      for (int i = 0; i < TM; ++i)
#pragma unroll
        for (int j = 0; j < TN; ++j) acc[i][j] = fmaf(a[i], bb[j], acc[i][j]);
    }
    __syncthreads();
  }

#pragma unroll
  for (int i = 0; i < TM; ++i) {
    int m = m0 + ty * TM + i;
    if (m >= M) continue;
    if constexpr ((TN & 3) == 0) {
#pragma unroll
      for (int j0 = 0; j0 < TN; j0 += 4) {
        int n = n0 + tx * TN + j0;
        float v[4];
#pragma unroll
        for (int t = 0; t < 4; ++t) {
          float xv = acc[i][j0 + t];
          if (epi == 1) xv = softplusf_(xv + bias[n + t]);
          else if (epi == 2) xv = seluf_(xv);
          v[t] = xv;
        }
        if (epi == 3) {
#pragma unroll
          for (int t = 0; t < 4; ++t)
            if (n + t < N) atomicAdd(&C[(size_t)m * ldc + n + t], v[t]);
        } else if (n + 3 < N) {
          *(float4*)&C[(size_t)m * ldc + n] = make_float4(v[0], v[1], v[2], v[3]);
        } else {
#pragma unroll
          for (int t = 0; t < 4; ++t)
            if (n + t < N) C[(size_t)m * ldc + n + t] = v[t];
        }
      }
    } else {
#pragma unroll
      for (int j = 0; j < TN; ++j) {
        int n = n0 + tx * TN + j;
        if (n >= N) continue;
        float v = acc[i][j];
        if (epi == 1) v = softplusf_(v + bias[n]);
        else if (epi == 2) v = seluf_(v);
        if (epi == 3) atomicAdd(&C[(size_t)m * ldc + n], v);
        else C[(size_t)m * ldc + n] = v;
      }
    }
  }
}

// ---------------------------------------------------------------------------
// Depthwise causal conv1d (width 4) + bias + silu -> xc.
// ALSO replaces the z-half of xz with silu(z) in place (scan consumes it raw).
// ---------------------------------------------------------------------------
__global__ __launch_bounds__(256) void conv_silu(
    float* __restrict__ xz, const float* __restrict__ cw,
    const float* __restrict__ cb, float* __restrict__ xc)
{
  int id = blockIdx.x * 256 + threadIdx.x;
  if (id >= BL * 1024) return;
  int bl = id >> 10;
  int d = id & 1023;
  int l = bl % T_;
  float4 w4 = *(const float4*)(cw + d * 4);
  float s = cb[d];
  if (l >= 3) s = fmaf(xz[(size_t)(bl - 3) * 2048 + d], w4.x, s);
  if (l >= 2) s = fmaf(xz[(size_t)(bl - 2) * 2048 + d], w4.y, s);
  if (l >= 1) s = fmaf(xz[(size_t)(bl - 1) * 2048 + d], w4.z, s);
  s = fmaf(xz[(size_t)bl * 2048 + d], w4.w, s);
  xc[id] = siluf_(s);
  float z = xz[(size_t)bl * 2048 + 1024 + d];
  xz[(size_t)bl * 2048 + 1024 + d] = siluf_(z);
}

// ---------------------------------------------------------------------------
// Selective scan v3. Wave = 2 channels x (32 lanes x 2 states). 4096 waves.
// DPP reduction; depth-2 prefetch; reads precomputed silu(z).
// ---------------------------------------------------------------------------
__global__ __launch_bounds__(256) void scan_kernel(
    const float* __restrict__ dtb, const float* __restrict__ xc,
    const float* __restrict__ xdbl, float* __restrict__ xz,
    const float* __restrict__ A_log, const float* __restrict__ Dp)
{
  int tid = threadIdx.x;
  int wv = tid >> 6, lane = tid & 63;
  int c = lane >> 5;          // channel within the pair
  int u = lane & 31;          // state-pair index (states 2u, 2u+1)
  int w = blockIdx.x * 4 + wv;    // 0..4095
  int b = w >> 9;                 // batch
  int d = ((w & 511) << 1) + c;   // channel
  const float LOG2E = 1.4426950408889634f;
  float2 al = *(const float2*)(A_log + (size_t)d * 64 + u * 2);
  float am0 = -expf(al.x) * LOG2E;
  float am1 = -expf(al.y) * LOG2E;
  float Dv = Dp[d];
  float h0 = 0.f, h1 = 0.f;
  const float* dtp = dtb + (size_t)b * 256000 + d;
  const float* xp  = xc  + (size_t)b * 256000 + d;
  const float* zp  = xz  + (size_t)b * 512000 + 1024 + d;   // silu(z)
  float*       yp  = xz  + (size_t)b * 512000 + d;
  const float* bp  = xdbl + (size_t)b * 40000 + 32 + u * 2;
  const float* cp  = bp + 64;

  float dt_f[2], xv_f[2], sz_f[2];
  float2 B_f[2], C_f[2];
#pragma unroll
  for (int i = 0; i < 2; ++i) {
    dt_f[i] = dtp[i * 1024];
    xv_f[i] = xp[i * 1024];
    sz_f[i] = zp[i * 2048];
    B_f[i] = *(const float2*)(bp + i * 160);
    C_f[i] = *(const float2*)(cp + i * 160);
  }
  const bool outlane = (u == 16);   // lanes 16 and 48

#pragma unroll 2
  for (int l = 0; l < T_; ++l) {
    int slot = l & 1;
    float dt = dt_f[slot], xv = xv_f[slot], sz = sz_f[slot];
    float2 Bv = B_f[slot], Cv = C_f[slot];
    // prefetch step l+2 (unconditional; overreads stay inside d_ws)
    dt_f[slot] = dtp[(size_t)(l + 2) * 1024];
    xv_f[slot] = xp[(size_t)(l + 2) * 1024];
    sz_f[slot] = zp[(size_t)(l + 2) * 2048];
    B_f[slot]  = *(const float2*)(bp + (size_t)(l + 2) * 160);
    C_f[slot]  = *(const float2*)(cp + (size_t)(l + 2) * 160);

    float dtx = dt * xv;
    h0 = fmaf(h0, exp2f(dt * am0), dtx * Bv.x);
    h1 = fmaf(h1, exp2f(dt * am1), dtx * Bv.y);
    float p = fmaf(h1, Cv.y, h0 * Cv.x);
    p = dpp_add<0xB1>(p);    // xor 1
    p = dpp_add<0x4E>(p);    // xor 2
    p = dpp_add<0x124>(p);   // row_ror:4
    p = dpp_add<0x128>(p);   // row_ror:8  -> row sums in all 16 lanes
    p = dpp_add<0x142>(p);   // row_bcast15 -> ch totals on lanes 16-31 / 48-63
    if (outlane) yp[(size_t)l * 2048] = fmaf(xv, Dv, p) * sz;
  }
}

// ---------------------------------------------------------------------------
// Permute selu(out_proj) [2000][480] -> y_flat [8][120000] (f-major)
// ---------------------------------------------------------------------------
__global__ __launch_bounds__(256) void transpose_k(
    const float* __restrict__ ym, float* __restrict__ yfl)
{
  int id = blockIdx.x * 256 + threadIdx.x;
  if (id >= 8 * NFLAT) return;
  int b = id / NFLAT;
  int r = id % NFLAT;
  int f = r / 5000;
  int qq = r % 5000;
  int tt = qq / 20;
  int p = qq % 20;
  yfl[id] = ym[(size_t)(b * T_ + tt) * KIN + p * 24 + f];
}

// ---------------------------------------------------------------------------
// fc1 v3: r1[b][c] += sum_k yfl[b][k] * W1[c][k].
// Wave = 4 c-rows x 8 batches (acc[4][8]); per k-step of 256 floats:
// 4 W float4 + 8 y float4 = 12 independent loads, 128 FMAs.
// 768 blocks = 32 c-groups(16 rows) x 24 k-slices(5000) -> 12 waves/CU.
// ---------------------------------------------------------------------------
__global__ __launch_bounds__(256) void fc1_kernel(
    const float* __restrict__ yfl, const float* __restrict__ W,
    float* __restrict__ r1)
{
  int blk = blockIdx.x;
  int ks = blk % 24;           // k-slice: [ks*5000, ks*5000+5000)
  int cg = blk / 24;           // 0..31
  int wv = threadIdx.x >> 6;
  int lane = threadIdx.x & 63;
  int c0 = cg * 16 + wv * 4;
  const float* W0 = W + (size_t)c0 * NFLAT;
  float acc[4][8];
#pragma unroll
  for (int cc = 0; cc < 4; ++cc)
#pragma unroll
    for (int b = 0; b < 8; ++b) acc[cc][b] = 0.0f;

  int kbase = ks * 5000;
  int kend = kbase + 5000;
  for (int k = kbase + lane * 4; k + 4 <= kend; k += 256) {
    float4 w0 = *(const float4*)(W0 + k);
    float4 w1 = *(const float4*)(W0 + NFLAT + k);
    float4 w2 = *(const float4*)(W0 + 2 * (size_t)NFLAT + k);
    float4 w3 = *(const float4*)(W0 + 3 * (size_t)NFLAT + k);
#pragma unroll
    for (int b = 0; b < 8; ++b) {
      float4 y = *(const float4*)(yfl + (size_t)b * NFLAT + k);
      acc[0][b] = fmaf(w0.x, y.x, fmaf(w0.y, y.y, fmaf(w0.z, y.z, fmaf(w0.w, y.w, acc[0][b]))));
      acc[1][b] = fmaf(w1.x, y.x, fmaf(w1.y, y.y, fmaf(w1.z, y.z, fmaf(w1.w, y.w, acc[1][b]))));
      acc[2][b] = fmaf(w2.x, y.x, fmaf(w2.y, y.y, fmaf(w2.z, y.z, fmaf(w2.w, y.w, acc[2][b]))));
      acc[3][b] = fmaf(w3.x, y.x, fmaf(w3.y, y.y, fmaf(w3.z, y.z, fmaf(w3.w, y.w, acc[3][b]))));
    }
  }
#pragma unroll
  for (int cc = 0; cc < 4; ++cc)
#pragma unroll
    for (int b = 0; b < 8; ++b) {
      float s = acc[cc][b];
      s += __shfl_xor(s, 1);
      s += __shfl_xor(s, 2);
      s += __shfl_xor(s, 4);
      s += __shfl_xor(s, 8);
      s += __shfl_xor(s, 16);
      s += __shfl_xor(s, 32);
      if (lane == 0) atomicAdd(&r1[b * 512 + c0 + cc], s);
    }
}

// ---------------------------------------------------------------------------
// fc2: one wave per output (b,j): dot-512 + biases
// ---------------------------------------------------------------------------
__global__ __launch_bounds__(256) void fc2_kernel(
    const float* __restrict__ r1, const float* __restrict__ b1,
    const float* __restrict__ W2, const float* __restrict__ b2,
    float* __restrict__ r2)
{
  int wid = blockIdx.x * 4 + (threadIdx.x >> 6);   // 0..2047
  int lane = threadIdx.x & 63;
  int b = wid >> 8;
  int j = wid & 255;
  int off = lane * 8;
  float4 ya = *(const float4*)(r1 + b * 512 + off);
  float4 yb = *(const float4*)(r1 + b * 512 + off + 4);
  float4 ba = *(const float4*)(b1 + off);
  float4 bbv = *(const float4*)(b1 + off + 4);
  float4 wa = *(const float4*)(W2 + (size_t)j * 512 + off);
  float4 wb = *(const float4*)(W2 + (size_t)j * 512 + off + 4);
  float p = (ya.x + ba.x) * wa.x + (ya.y + ba.y) * wa.y +
            (ya.z + ba.z) * wa.z + (ya.w + ba.w) * wa.w +
            (yb.x + bbv.x) * wb.x + (yb.y + bbv.y) * wb.y +
            (yb.z + bbv.z) * wb.z + (yb.w + bbv.w) * wb.w;
  p += __shfl_xor(p, 1);
  p += __shfl_xor(p, 2);
  p += __shfl_xor(p, 4);
  p += __shfl_xor(p, 8);
  p += __shfl_xor(p, 16);
  p += __shfl_xor(p, 32);
  if (lane == 0) r2[b * 256 + j] = p + b2[j];
}

// ---------------------------------------------------------------------------
// fc3 + fc4 fused, single block
// ---------------------------------------------------------------------------
__global__ __launch_bounds__(256) void fc34_kernel(
    const float* __restrict__ r2, const float* __restrict__ W3,
    const float* __restrict__ b3, const float* __restrict__ W4,
    const float* __restrict__ b4, float* __restrict__ out)
{
  __shared__ float a3[512];
  int tid = threadIdx.x;
  for (int o = tid; o < 512; o += 256) {
    int b = o >> 6, j = o & 63;
    float s = b3[j];
    const float* rr = r2 + b * 256;
    const float* wr = W3 + j * 256;
    for (int c = 0; c < 256; c += 4) {
      float4 rv = *(const float4*)(rr + c);
      float4 wv = *(const float4*)(wr + c);
      s = fmaf(rv.x, wv.x, fmaf(rv.y, wv.y, fmaf(rv.z, wv.z, fmaf(rv.w, wv.w, s))));
    }
    a3[o] = s;
  }
  __syncthreads();
  if (tid < 64) {
    int b = tid >> 3, j = tid & 7;
    float s = b4[j];
    const float* ar = a3 + b * 64;
    const float* wr = W4 + j * 64;
    for (int c = 0; c < 64; ++c) s = fmaf(ar[c], wr[c], s);
    out[b * 8 + j] = s;
  }
}

// ---------------------------------------------------------------------------
extern "C" void kernel_launch(void* const* d_in, const int* in_sizes, int n_in,
                              void* d_out, int out_size, void* d_ws, size_t ws_size,
                              hipStream_t stream) {
  const float* x      = (const float*)d_in[0];   // [8,5000,24] == [2000][480]
  const float* w_in   = (const float*)d_in[1];   // [2048,512]
  const float* conv_w = (const float*)d_in[2];   // [1024,4]
  const float* conv_b = (const float*)d_in[3];   // [1024]
  const float* w_xp   = (const float*)d_in[4];   // [160,1024]
  const float* w_dt   = (const float*)d_in[5];   // [1024,32]
  const float* b_dt   = (const float*)d_in[6];   // [1024]
  const float* A_log  = (const float*)d_in[7];   // [1024,64]
  const float* Dp     = (const float*)d_in[8];   // [1024]
  const float* w_out  = (const float*)d_in[9];   // [512,1024]
  const float* w1 = (const float*)d_in[10];      // [512,120000]
  const float* b1 = (const float*)d_in[11];
  const float* w2 = (const float*)d_in[12];      // [256,512]
  const float* b2 = (const float*)d_in[13];
  const float* w3 = (const float*)d_in[14];      // [64,256]
  const float* b3 = (const float*)d_in[15];
  const float* w4 = (const float*)d_in[16];      // [8,64]
  const float* b4 = (const float*)d_in[17];
  float* out = (float*)d_out;

  float* ws   = (float*)d_ws;
  float* xz   = ws;                 // [2000][2048]  (x half -> gated y; z half -> silu(z))
  float* xc   = xz + 4096000;       // [2000][1024]
  float* dtb  = xc + 2048000;       // [2000][1024]
  float* ym   = dtb + 2048000;      // [2000][480]
  float* yfl  = ym + 960000;        // [8][120000]
  float* xdbl = yfl + 960000;       // [2000][160]
  float* r1   = xdbl + 320000;      // [8][512]
  float* r2   = r1 + 4096;          // [8][256]

  // zero the atomic accumulators (xdbl + r1, contiguous)
  hipMemsetAsync(xdbl, 0, (320000 + 4096) * sizeof(float), stream);

  // 1. in_proj: xz[2000][2048] = x[2000][480] @ Win[2048][512(^480)]^T
  gemm_nt<64, 128, 32, 4, 8><<<dim3(2048 / 128, (BL + 63) / 64, 1), 256, 0, stream>>>(
      x, w_in, xz, nullptr, BL, 2048, KIN, KIN, 512, 2048, 0);

  // 2. depthwise conv + silu (also silu's the z-half in place)
  conv_silu<<<(BL * 1024) / 256, 256, 0, stream>>>(xz, conv_w, conv_b, xc);

  // 3. x_proj (split-K=2, atomic): xdbl[2000][160] = xc @ Wxp^T
  gemm_nt<32, 64, 32, 1, 8><<<dim3(3, (BL + 31) / 32, 2), 256, 0, stream>>>(
      xc, w_xp, xdbl, nullptr, BL, 160, 1024, 1024, 1024, 160, 3);

  // 4. dt_proj + softplus: dtb[2000][1024] = softplus(xdbl[:, :32] @ Wdt^T + b_dt)
  gemm_nt<32, 64, 32, 1, 8><<<dim3(1024 / 64, (BL + 31) / 32, 1), 256, 0, stream>>>(
      xdbl, w_dt, dtb, b_dt, BL, 1024, 32, 160, 32, 1024, 1);

  // 5. selective scan -> gated y into xz x-half
  scan_kernel<<<1024, 256, 0, stream>>>(dtb, xc, xdbl, xz, A_log, Dp);

  // 6. out_proj + selu: ym[2000][480] = selu(yg @ Wout[480 rows]^T)
  gemm_nt<64, 64, 32, 4, 4><<<dim3((KIN + 63) / 64, (BL + 63) / 64, 1), 256, 0, stream>>>(
      xz, w_out, ym, nullptr, BL, KIN, 1024, 2048, 1024, KIN, 2);

  // 7. permute to y_flat
  transpose_k<<<(8 * NFLAT) / 256, 256, 0, stream>>>(ym, yfl);

  // 8. fc1 (atomic accumulate into r1)
  fc1_kernel<<<768, 256, 0, stream>>>(yfl, w1, r1);

  // 9. fc2
  fc2_kernel<<<512, 256, 0, stream>>>(r1, b1, w2, b2, r2);

  // 10. fc3 + fc4
  fc34_kernel<<<1, 256, 0, stream>>>(r2, w3, b3, w4, b4, out);
}